// Round 6
// baseline (28014.227 us; speedup 1.0000x reference)
//
#include <hip/hip_runtime.h>

#define NT 2048
#define NI 128
#define NH 256
#define WPG 32
#define BPG 8
#define ZROW 640  // [x(128) | h0(256) | h1(256)]

typedef unsigned long long u64;

__device__ __forceinline__ float sigm(float v) {
  return 1.0f / (1.0f + __expf(-v));
}
__device__ __forceinline__ float tanh_fast(float v) {
  v = fminf(fmaxf(v, -15.0f), 15.0f);
  float e = __expf(-2.0f * v);
  return (1.0f - e) / (1.0f + e);
}
__device__ __forceinline__ float lstm_act(float gi, float gf, float gg, float go,
                                          float& c) {
  const float ii = sigm(gi), ff = sigm(gf), gt = tanh_fast(gg), oo = sigm(go);
  c = ff * c + ii * gt;
  return oo * tanh_fast(c);
}

// relaxed agent-scope => coherent across XCDs, NO cache-maintenance ops.
__device__ __forceinline__ int ld_flag(const int* p) {
  return __hip_atomic_load(p, __ATOMIC_RELAXED, __HIP_MEMORY_SCOPE_AGENT);
}
__device__ __forceinline__ void st_flag(int* p, int v) {
  __hip_atomic_store(p, v, __ATOMIC_RELAXED, __HIP_MEMORY_SCOPE_AGENT);
}
__device__ __forceinline__ void st_h32(float* p, float v) {
  __hip_atomic_store(p, v, __ATOMIC_RELAXED, __HIP_MEMORY_SCOPE_AGENT);
}
__device__ __forceinline__ u64 ld_h64(const u64* p) {
  return __hip_atomic_load(p, __ATOMIC_RELAXED, __HIP_MEMORY_SCOPE_AGENT);
}

template <int CTRL>
__device__ __forceinline__ float dppadd(float x) {
  int s = __builtin_amdgcn_update_dpp(0, __float_as_int(x), CTRL, 0xf, 0xf, true);
  return x + __int_as_float(s);
}
__device__ __forceinline__ float red16(float v) {
  v = dppadd<0xB1>(v);   // lane ^ 1
  v = dppadd<0x4E>(v);   // lane ^ 2
  v = dppadd<0x141>(v);  // lane ^ 7 (row_half_mirror)
  v = dppadd<0x140>(v);  // lane ^ 15 (row_mirror)
  return v;
}

// lgkm-only barrier: LDS ordering without draining the vm (prefetch) queue.
__device__ __forceinline__ void bar_lgkm() {
  asm volatile("s_waitcnt lgkmcnt(0)" ::: "memory");
  __builtin_amdgcn_s_barrier();
  asm volatile("" ::: "memory");
}

// 256 WGs x 512 threads, 1 WG/CU (96KB dyn LDS). Group g=bid&7: batches
// [8g,8g+8); WG j=bid>>3: units [8j,8j+8) of both layers, weights in VGPRs.
// Halves A/B (4 batches each) alternate; layer-skewed (phase computes L0(it),
// L1(it-1)). Per half-phase: stage -> B1 -> [wave1: deferred vmcnt+flag for
// PREVIOUS phase's publish] -> dot+DPP+act+gat -> poll(other half, after dot:
// one dot of cover for flag RT) -> prefetch (rides across B2) -> B2 ->
// [wave1: coalesced 128B/layer publish store, ack drains off-path].
__global__ __launch_bounds__(512, 1) void lstm_persistent(
    const float* __restrict__ x,
    const float* __restrict__ wih0, const float* __restrict__ whh0,
    const float* __restrict__ bih0, const float* __restrict__ bhh0,
    const float* __restrict__ wih1, const float* __restrict__ whh1,
    const float* __restrict__ bih1, const float* __restrict__ bhh1,
    const float* __restrict__ fcw, const float* __restrict__ fcb,
    float* __restrict__ out,
    float* __restrict__ h0buf, float* __restrict__ h1buf,
    int* __restrict__ flags)
{
  extern __shared__ float sm[];
  float* zz  = sm;             // [4][ZROW]
  float* gat = sm + 4 * ZROW;  // [2][4][8] = [layer][b_loc][u]

  const int tid = threadIdx.x;
  const int bid = blockIdx.x;
  const int g = bid & 7;
  const int j = bid >> 3;
  const int b0 = g * BPG;
  int* fA = flags + g * WPG;
  int* fB = flags + 256 + g * WPG;

  const bool isL0 = (tid < 256);
  const int lane = tid & 63;
  const int wv = (tid & 255) >> 6;  // wave-in-layer 0..3
  const int ks = lane & 15;         // k-slice
  const int rg2 = (lane >> 4) & 1;  // unit-in-wave
  const int bg = lane >> 5;         // batch-pair
  const int u = wv * 2 + rg2;       // unit-local 0..7
  const int sel = ks & 1;           // lane's batch parity (act dedup)
  const int myb = bg * 2 + sel;     // lane's local batch 0..3

  // ---- weights + bias into registers (k = ks*4 + 64*c + e) ----
  float w[4][32];
  float bs[4];
  if (isL0) {
#pragma unroll
    for (int gt = 0; gt < 4; ++gt) {
      const int R = gt * NH + j * 8 + u;
      bs[gt] = bih0[R] + bhh0[R];
#pragma unroll
      for (int c = 0; c < 6; ++c)
#pragma unroll
        for (int e = 0; e < 4; ++e) {
          const int k = ks * 4 + 64 * c + e;
          w[gt][c * 4 + e] = (k < NI) ? wih0[R * NI + k] : whh0[R * NH + (k - NI)];
        }
#pragma unroll
      for (int q = 24; q < 32; ++q) w[gt][q] = 0.0f;
    }
  } else {
#pragma unroll
    for (int gt = 0; gt < 4; ++gt) {
      const int R = gt * NH + j * 8 + u;
      bs[gt] = bih1[R] + bhh1[R];
#pragma unroll
      for (int c = 0; c < 8; ++c)
#pragma unroll
        for (int e = 0; e < 4; ++e) {
          const int k = ks * 4 + 64 * c + e;
          w[gt][c * 4 + e] = (k < NH) ? wih1[R * NH + k] : whh1[R * NH + (k - NH)];
        }
    }
  }

  // ---- hoisted per-thread constants ----
  const int pj = tid >> 4;  // j' 0..31 (stage/prefetch role)
  const int pr = tid & 15;
  const int pb = pr >> 2;   // local batch 0..3
  const int pu = pr & 3;    // u-pair 0..3
  const int stage_h0 = pb * ZROW + 128 + pj * 8 + pu * 2;
  const int stage_h1 = pb * ZROW + 384 + pj * 8 + pu * 2;
  const int pre_base = (g * 32 + pj) * 64 + pb * 8 + pu * 2;  // +oxb*8 +par*16384
  const float* xA = x + (size_t)(b0 + 0 + (tid >> 5)) * NT * NI + (tid & 31) * 4;
  const float* xB = x + (size_t)(b0 + 4 + (tid >> 5)) * NT * NI + (tid & 31) * 4;
  const bool isW1 = ((tid >> 6) == 1);

  float cA = 0.f, cB = 0.f;  // cell for (u, myb) per half
  u64 rh0 = 0, rh1 = 0;
  float4 xv = make_float4(0.f, 0.f, 0.f, 0.f);
  if (tid < 128) xv = *reinterpret_cast<const float4*>(xA);  // (0,A)
  __syncthreads();

#pragma unroll 1
  for (int it = 0; it <= NT; ++it) {
#pragma unroll
    for (int half = 0; half < 2; ++half) {
      const int xb = half ? 4 : 0;
      const int oxb = half ? 0 : 4;
      const int nit = half ? it + 1 : it;  // prefetch-target iteration
      int* fOther = half ? fA : fB;

      // ---- S1: stage regs -> LDS ----
      if (tid < 128 && it < NT)
        *reinterpret_cast<float4*>(&zz[(tid >> 5) * ZROW + (tid & 31) * 4]) = xv;
      *reinterpret_cast<u64*>(&zz[stage_h0]) = rh0;
      *reinterpret_cast<u64*>(&zz[stage_h1]) = rh1;
      bar_lgkm();  // B1 (vm queue NOT drained)

      // ---- deferred publish-drain + flag for the PREVIOUS half-phase ----
      if (isW1) {
        asm volatile("s_waitcnt vmcnt(0)" ::: "memory");  // prev store ack'd
        if (tid == 64) {
          if (half) st_flag(&fA[j], it + 1);      // prev = (it, A)
          else if (it >= 1) st_flag(&fB[j], it);  // prev = (it-1, B)
        }
      }

      // ---- S2: dot + DPP k-reduce + act + gat write ----
      if (isL0 ? (it < NT) : (it >= 1)) {
        float acc[4][2] = {{0.f, 0.f}, {0.f, 0.f}, {0.f, 0.f}, {0.f, 0.f}};
        const int koff = isL0 ? (ks * 4) : (128 + ks * 4);
        const float* z0 = &zz[(bg * 2 + 0) * ZROW + koff];
        const float* z1 = &zz[(bg * 2 + 1) * ZROW + koff];
        const int NC = isL0 ? 6 : 8;
#pragma unroll
        for (int c = 0; c < 8; ++c) {
          if (c < NC) {
            const float4 v0 = *reinterpret_cast<const float4*>(z0 + 64 * c);
            const float4 v1 = *reinterpret_cast<const float4*>(z1 + 64 * c);
#pragma unroll
            for (int gt = 0; gt < 4; ++gt) {
              acc[gt][0] = fmaf(w[gt][c * 4 + 0], v0.x, acc[gt][0]);
              acc[gt][0] = fmaf(w[gt][c * 4 + 1], v0.y, acc[gt][0]);
              acc[gt][0] = fmaf(w[gt][c * 4 + 2], v0.z, acc[gt][0]);
              acc[gt][0] = fmaf(w[gt][c * 4 + 3], v0.w, acc[gt][0]);
              acc[gt][1] = fmaf(w[gt][c * 4 + 0], v1.x, acc[gt][1]);
              acc[gt][1] = fmaf(w[gt][c * 4 + 1], v1.y, acc[gt][1]);
              acc[gt][1] = fmaf(w[gt][c * 4 + 2], v1.z, acc[gt][1]);
              acc[gt][1] = fmaf(w[gt][c * 4 + 3], v1.w, acc[gt][1]);
            }
          }
        }
        float s0[4];
#pragma unroll
        for (int gt = 0; gt < 4; ++gt) {
          const float ra = red16(acc[gt][0]);
          const float rb = red16(acc[gt][1]);
          s0[gt] = (sel ? rb : ra) + bs[gt];
        }
        float c = half ? cB : cA;
        const float h = lstm_act(s0[0], s0[1], s0[2], s0[3], c);
        if (half) cB = c; else cA = c;
        if (ks < 2) gat[(isL0 ? 0 : 32) + myb * 8 + u] = h;
      }

      // ---- S3: poll (after dot: peer flag had stage+dot to propagate) ----
      if (nit >= 1 && nit <= NT && lane < WPG) {
        int guard = 0;
        while (ld_flag(&fOther[lane]) < nit) {
          __builtin_amdgcn_s_sleep(1);
          if (++guard > 50000000) break;
        }
      }
      asm volatile("" ::: "memory");  // keep prefetch below the poll

      // ---- S4: prefetch next phase's h0/h1/x (rides across B2) ----
      if (nit <= NT) {
        const int o0 = ((nit - 1) & 1) * 16384 + oxb * 8 + pre_base;
        const int o1 = (nit & 1) * 16384 + oxb * 8 + pre_base;
        rh0 = ld_h64(reinterpret_cast<const u64*>(h0buf + o0));
        rh1 = ld_h64(reinterpret_cast<const u64*>(h1buf + o1));
        if (tid < 128 && nit < NT) {
          xv = *reinterpret_cast<const float4*>((half ? xA : xB) +
                                                (size_t)nit * NI);
        }
      }

      bar_lgkm();  // B2 (gat visible; prefetches stay in flight)

      // ---- S5: wave1 coalesced publish (128B per layer); ack drains
      //          off-path, flag deferred to next phase post-B1 ----
      if (isW1) {
        const int layer = lane >> 5, idx = lane & 31;
        const bool ok = layer ? (it >= 1) : (it < NT);
        if (ok) {
          const int par = layer ? ((it - 1) & 1) : (it & 1);
          float* hb = layer ? h1buf : h0buf;
          st_h32(hb + par * 16384 + (g * 32 + j) * 64 + (xb + (idx >> 3)) * 8 +
                     (idx & 7),
                 gat[lane]);
        }
      }
    }
  }

  // ---- tail: final flag for (NT, B) ----
  if (isW1) {
    asm volatile("s_waitcnt vmcnt(0)" ::: "memory");
    if (tid == 64) st_flag(&fB[j], NT + 1);
  }

  // ---- epilogue: FC over relu(h1[T-1]) by WG j==0 of each group ----
  if (j == 0) {
    if (tid < WPG) {
      int guard = 0;
      while (ld_flag(&fA[tid]) < NT + 1 || ld_flag(&fB[tid]) < NT + 1) {
        __builtin_amdgcn_s_sleep(1);
        if (++guard > 50000000) break;
      }
    }
    __syncthreads();
    const int bb = tid >> 6, ln = tid & 63;  // 8 waves = 8 batches
    const int jj = ln >> 1, q = ln & 1;      // 4 cols per lane = ln*4..ln*4+3
    const float* src = h1buf + 16384 + (g * 32 + jj) * 64 + bb * 8 + q * 4;
    const u64 u0 = ld_h64(reinterpret_cast<const u64*>(src));
    const u64 u1 = ld_h64(reinterpret_cast<const u64*>(src + 2));
    const float ha = __uint_as_float((unsigned)u0);
    const float hb = __uint_as_float((unsigned)(u0 >> 32));
    const float hc = __uint_as_float((unsigned)u1);
    const float hd = __uint_as_float((unsigned)(u1 >> 32));
    const float4 w4 = *reinterpret_cast<const float4*>(fcw + ln * 4);
    float p = fmaxf(ha, 0.f) * w4.x + fmaxf(hb, 0.f) * w4.y +
              fmaxf(hc, 0.f) * w4.z + fmaxf(hd, 0.f) * w4.w;
#pragma unroll
    for (int off = 32; off >= 1; off >>= 1) p += __shfl_down(p, off, 64);
    if (ln == 0) out[b0 + bb] = p + fcb[0];
  }
}

extern "C" void kernel_launch(void* const* d_in, const int* in_sizes, int n_in,
                              void* d_out, int out_size, void* d_ws, size_t ws_size,
                              hipStream_t stream) {
  (void)in_sizes; (void)n_in; (void)out_size; (void)ws_size;
  const float* x    = (const float*)d_in[0];
  const float* wih0 = (const float*)d_in[1];
  const float* whh0 = (const float*)d_in[2];
  const float* bih0 = (const float*)d_in[3];
  const float* bhh0 = (const float*)d_in[4];
  const float* wih1 = (const float*)d_in[5];
  const float* whh1 = (const float*)d_in[6];
  const float* bih1 = (const float*)d_in[7];
  const float* bih1b = bih1; (void)bih1b;
  const float* bhh1 = (const float*)d_in[8];
  const float* fcw  = (const float*)d_in[9];
  const float* fcb  = (const float*)d_in[10];
  float* out = (float*)d_out;

  float* ws = (float*)d_ws;
  float* h0buf = ws;                      // [2][8][32][8][8] f32 = 32768
  float* h1buf = ws + 32768;              // [2][8][32][8][8] f32
  int* flags = (int*)(ws + 65536);        // [2][8][32]

  const size_t zbytes = (size_t)65536 * sizeof(float) + 512 * sizeof(int);
  hipMemsetAsync(d_ws, 0, zbytes, stream);

  size_t shmem = 96 * 1024;  // force 1 WG/CU (co-residency, CU exclusivity)
  if (hipFuncSetAttribute(reinterpret_cast<const void*>(lstm_persistent),
                          hipFuncAttributeMaxDynamicSharedMemorySize,
                          (int)shmem) != hipSuccess) {
    shmem = (4 * ZROW + 64) * sizeof(float);  // real footprint fallback
  }

  hipLaunchKernelGGL(lstm_persistent, dim3(256), dim3(512), shmem, stream,
                     x, wih0, whh0, bih0, bhh0, wih1, whh1, bih1, bhh1,
                     fcw, fcb, out, h0buf, h1buf, flags);
}

// Round 7
// 24519.519 us; speedup vs baseline: 1.1425x; 1.1425x over previous
//
#include <hip/hip_runtime.h>

#define NT 2048
#define NI 128
#define NH 256
#define BPG 8
#define HST 260  // LDS h row stride (floats)
#define XST 132  // LDS x row stride

typedef unsigned long long u64;

__device__ __forceinline__ float sigm(float v) {
  return 1.0f / (1.0f + __expf(-v));
}
__device__ __forceinline__ float tanh_fast(float v) {
  v = fminf(fmaxf(v, -15.0f), 15.0f);
  float e = __expf(-2.0f * v);
  return (1.0f - e) / (1.0f + e);
}
__device__ __forceinline__ float lstm_act(float gi, float gf, float gg, float go,
                                          float& c) {
  const float ii = sigm(gi), ff = sigm(gf), gt = tanh_fast(gg), oo = sigm(go);
  c = ff * c + ii * gt;
  return oo * tanh_fast(c);
}

// relaxed agent-scope: cross-XCD coherent, no cache-maintenance ops
__device__ __forceinline__ int ld_flag(const int* p) {
  return __hip_atomic_load(p, __ATOMIC_RELAXED, __HIP_MEMORY_SCOPE_AGENT);
}
__device__ __forceinline__ void st_flag(int* p, int v) {
  __hip_atomic_store(p, v, __ATOMIC_RELAXED, __HIP_MEMORY_SCOPE_AGENT);
}
__device__ __forceinline__ u64 ld_h64(const u64* p) {
  return __hip_atomic_load(p, __ATOMIC_RELAXED, __HIP_MEMORY_SCOPE_AGENT);
}
__device__ __forceinline__ void st_h64(u64* p, u64 v) {
  __hip_atomic_store(p, v, __ATOMIC_RELAXED, __HIP_MEMORY_SCOPE_AGENT);
}

template <int CTRL>
__device__ __forceinline__ float dppadd(float x) {
  int s = __builtin_amdgcn_update_dpp(0, __float_as_int(x), CTRL, 0xf, 0xf, true);
  return x + __int_as_float(s);
}
__device__ __forceinline__ float red16(float v) {
  v = dppadd<0xB1>(v);   // ^1
  v = dppadd<0x4E>(v);   // ^2
  v = dppadd<0x141>(v);  // ^7
  v = dppadd<0x140>(v);  // ^15
  return v;
}

__device__ __forceinline__ void bar_lgkm() {
  asm volatile("s_waitcnt lgkmcnt(0)" ::: "memory");
  __builtin_amdgcn_s_barrier();
  asm volatile("" ::: "memory");
}

// 16 FMAs: 4 batches x 4 gates for one k-chunk cc; weights at flat col wc4
__device__ __forceinline__ void dot4(float acc[4][4], const float* zrow0,
                                     const float* wr, int wc4, int rst, int cc) {
#pragma unroll
  for (int b = 0; b < 4; ++b) {
    const float4 v = *reinterpret_cast<const float4*>(zrow0 + b * rst + 64 * cc);
#pragma unroll
    for (int gt = 0; gt < 4; ++gt) {
      acc[gt][b] = fmaf(wr[gt * 32 + wc4 + 0], v.x, acc[gt][b]);
      acc[gt][b] = fmaf(wr[gt * 32 + wc4 + 1], v.y, acc[gt][b]);
      acc[gt][b] = fmaf(wr[gt * 32 + wc4 + 2], v.z, acc[gt][b]);
      acc[gt][b] = fmaf(wr[gt * 32 + wc4 + 3], v.w, acc[gt][b]);
    }
  }
}

// 256 WGs x 512 thr, 1 WG/CU. Group g=bid&7: batches [8g,8g+8); WG j=bid>>3:
// units [8j,8j+8) of both layers (weights in VGPRs; lanes = 16 k-slices x
// 2 units x 2 batch-quads, DPP k-reduce). SKEW-2: phase p computes L0(p) and
// L1(p-2) for all 8 batches (2050 phases total, one flag/phase).
// Phase: pre-seg1 (old data: L1*h0(p-2), L0*x(p)) || wave0 polls -> LDS
// doorbell -> all issue sc1 loads of h0(p-1),h1(p-3) -> post-seg1 (cover) ->
// land fresh in LDS -> B2 -> seg2 (L0*h0(p-1), L1*h1(p-3)) + red16 + act +
// gat -> B3 -> wave7 publishes (coalesced 256B/layer), drains, flags off-path.
__global__ __launch_bounds__(512, 1) void lstm_persistent(
    const float* __restrict__ x,
    const float* __restrict__ wih0, const float* __restrict__ whh0,
    const float* __restrict__ bih0, const float* __restrict__ bhh0,
    const float* __restrict__ wih1, const float* __restrict__ whh1,
    const float* __restrict__ bih1, const float* __restrict__ bhh1,
    const float* __restrict__ fcw, const float* __restrict__ fcb,
    float* __restrict__ out,
    float* __restrict__ h0buf, float* __restrict__ h1buf,
    int* __restrict__ flags)
{
  extern __shared__ float sm[];
  float* xs  = sm;                    // [2][8][XST]   x(p) at slot p&1
  float* h0s = sm + 2 * 8 * XST;      // [2][8][HST]
  float* h1s = h0s + 2 * 8 * HST;     // [8][HST]      h1(p-3), single buffer
  float* gat = h1s + 8 * HST;         // [2][2][64]    [par][layer][b*8+u]
  int* door  = (int*)(gat + 256);

  const int tid = threadIdx.x;
  const int bid = blockIdx.x;
  const int g = bid & 7;
  const int j = bid >> 3;
  const int b0 = g * BPG;
  int* fl = flags + g * 32;

  const int wave = tid >> 6, lane = tid & 63;
  const bool isL0 = (wave < 4);
  const int ks = lane & 15;
  const int u2 = (lane >> 4) & 1;
  const int bq = lane >> 5;
  const int u = (wave & 3) * 2 + u2;
  const int col = j * 8 + u;

  // ---- weights (flat [4][32]) + bias ----
  float w[4][32];
  float bs[4];
  if (isL0) {
#pragma unroll
    for (int gt = 0; gt < 4; ++gt) {
      const int R = gt * NH + col;
      bs[gt] = bih0[R] + bhh0[R];
#pragma unroll
      for (int c = 0; c < 6; ++c)
#pragma unroll
        for (int e = 0; e < 4; ++e) {
          const int k = ks * 4 + 64 * c + e;
          w[gt][c * 4 + e] = (k < NI) ? wih0[R * NI + k] : whh0[R * NH + (k - NI)];
        }
#pragma unroll
      for (int q = 24; q < 32; ++q) w[gt][q] = 0.0f;
    }
  } else {
#pragma unroll
    for (int gt = 0; gt < 4; ++gt) {
      const int R = gt * NH + col;
      bs[gt] = bih1[R] + bhh1[R];
#pragma unroll
      for (int c = 0; c < 8; ++c)
#pragma unroll
        for (int e = 0; e < 4; ++e) {
          const int k = ks * 4 + 64 * c + e;
          w[gt][c * 4 + e] = (k < NH) ? wih1[R * NH + k] : whh1[R * NH + (k - NH)];
        }
    }
  }
  const float* wr = &w[0][0];

  // x duty (tids 128..255): 8 floats each
  const int xt = tid - 128;
  const int xb = (xt >> 4) & 7, xo = (xt & 15) * 8;
  const float* xptr = x + (size_t)(b0 + xb) * NT * NI + xo;

  float cell = 0.0f;  // (u, b = bq*4 + (ks&3)) of this thread's layer
  float4 xva = make_float4(0.f, 0.f, 0.f, 0.f), xvb = xva;

  if (tid == 0) *door = 0;
  if (tid >= 128 && tid < 256) {       // stage x(0); preload x(1)
    const float4 a = *reinterpret_cast<const float4*>(xptr);
    const float4 b = *reinterpret_cast<const float4*>(xptr + 4);
    *reinterpret_cast<float4*>(&xs[xb * XST + xo]) = a;
    *reinterpret_cast<float4*>(&xs[xb * XST + xo + 4]) = b;
    xva = *reinterpret_cast<const float4*>(xptr + NI);
    xvb = *reinterpret_cast<const float4*>(xptr + NI + 4);
  }
  __syncthreads();

#pragma unroll 1
  for (int p = 0; p <= NT + 1; ++p) {
    const int par = p & 1;
    const float* h0_old = h0s + par * (8 * HST);        // h0(p-2)
    float* h0_new = h0s + (par ^ 1) * (8 * HST);        // h0(p-1) (landed below)
    const float* x_cur = xs + par * (8 * XST);          // x(p)
    const int fpar = (p >= 1) ? ((p - 1) & 1) : 1;      // zeros at p=0

    float acc[4][4];
#pragma unroll
    for (int a0 = 0; a0 < 4; ++a0)
#pragma unroll
      for (int a1 = 0; a1 < 4; ++a1) acc[a0][a1] = 0.0f;

    const float* zx = x_cur + bq * 4 * XST + ks * 4;
    const float* zo = h0_old + bq * 4 * HST + ks * 4;
    const float* zn = h0_new + bq * 4 * HST + ks * 4;
    const float* z1 = h1s + bq * 4 * HST + ks * 4;

    // ---- pre-seg1 (old data) ----
    if (isL0) {
      if (p < NT) dot4(acc, zx, wr, 0, XST, 0);
    } else {
      dot4(acc, zo, wr, 0, HST, 0);
      dot4(acc, zo, wr, 4, HST, 1);
    }

    // ---- poll (wave0) -> LDS doorbell ----
    if (wave == 0) {
      int guard = 0;
      for (;;) {
        const int v = (lane < 32) ? ld_flag(&fl[lane]) : 0x7fffffff;
        if (__all(v >= p)) break;
        __builtin_amdgcn_s_sleep(1);
        if (++guard > 50000000) break;
      }
      if (lane == 0)
        __hip_atomic_store(door, p + 1, __ATOMIC_RELAXED,
                           __HIP_MEMORY_SCOPE_WORKGROUP);
    } else if (wave != 7) {
      int guard = 0;
      while (__hip_atomic_load(door, __ATOMIC_RELAXED,
                               __HIP_MEMORY_SCOPE_WORKGROUP) < p + 1) {
        __builtin_amdgcn_s_sleep(0);
        if (++guard > 100000000) break;
      }
    }

    // ---- issue fresh sc1 loads: h0(p-1), h1(p-3) ----
    u64 ra0 = 0, ra1 = 0, ra2 = 0, ra3 = 0;
    u64 rb0 = 0, rb1 = 0, rb2 = 0, rb3 = 0;
    if (wave < 4) {
      const int li = (wave == 0) ? lane : tid;
      const u64* s = reinterpret_cast<const u64*>(
          h0buf + fpar * 16384 + g * 2048 + li * 8);
      ra0 = ld_h64(s); ra1 = ld_h64(s + 1); ra2 = ld_h64(s + 2); ra3 = ld_h64(s + 3);
      if (wave == 0) {
        const int li1 = 192 + lane;
        const u64* s2 = reinterpret_cast<const u64*>(
            h1buf + fpar * 16384 + g * 2048 + li1 * 8);
        rb0 = ld_h64(s2); rb1 = ld_h64(s2 + 1);
        rb2 = ld_h64(s2 + 2); rb3 = ld_h64(s2 + 3);
      }
    } else if (wave < 7) {
      const int li = tid - 256;
      const u64* s = reinterpret_cast<const u64*>(
          h1buf + fpar * 16384 + g * 2048 + li * 8);
      ra0 = ld_h64(s); ra1 = ld_h64(s + 1); ra2 = ld_h64(s + 2); ra3 = ld_h64(s + 3);
    }

    // ---- post-seg1 (covers load latency) ----
    if (isL0) {
      if (p < NT) dot4(acc, zx, wr, 4, XST, 1);
    } else {
      dot4(acc, zo, wr, 8, HST, 2);
      dot4(acc, zo, wr, 12, HST, 3);
    }

    // ---- land fresh into LDS; x stage+prefetch (waves 2-3) ----
    asm volatile("s_waitcnt vmcnt(0)" ::: "memory");
    if (wave < 4) {
      const int li = (wave == 0) ? lane : tid;
      float* d = h0_new + (li & 7) * HST + (li >> 3) * 8;
      u64* d64 = reinterpret_cast<u64*>(d);
      d64[0] = ra0; d64[1] = ra1; d64[2] = ra2; d64[3] = ra3;
      if (wave == 0) {
        const int li1 = 192 + lane;
        u64* e64 = reinterpret_cast<u64*>(h1s + (li1 & 7) * HST + (li1 >> 3) * 8);
        e64[0] = rb0; e64[1] = rb1; e64[2] = rb2; e64[3] = rb3;
      }
      if (wave >= 2) {
        if (p + 1 < NT) {  // xva/xvb hold x(p+1)
          float* xd = &xs[(par ^ 1) * (8 * XST) + xb * XST + xo];
          *reinterpret_cast<float4*>(xd) = xva;
          *reinterpret_cast<float4*>(xd + 4) = xvb;
        }
        if (p + 2 < NT) {
          xva = *reinterpret_cast<const float4*>(xptr + (size_t)(p + 2) * NI);
          xvb = *reinterpret_cast<const float4*>(xptr + (size_t)(p + 2) * NI + 4);
        }
      }
    } else if (wave < 7) {
      const int li = tid - 256;
      u64* d64 = reinterpret_cast<u64*>(h1s + (li & 7) * HST + (li >> 3) * 8);
      d64[0] = ra0; d64[1] = ra1; d64[2] = ra2; d64[3] = ra3;
    }
    bar_lgkm();  // B2 (x prefetch rides across)

    // ---- seg2 (fresh data) ----
    if (isL0) {
      if (p < NT) {
        dot4(acc, zn, wr, 8, HST, 0);
        dot4(acc, zn, wr, 12, HST, 1);
        dot4(acc, zn, wr, 16, HST, 2);
        dot4(acc, zn, wr, 20, HST, 3);
      }
    } else {
      dot4(acc, z1, wr, 16, HST, 0);
      dot4(acc, z1, wr, 20, HST, 1);
      dot4(acc, z1, wr, 24, HST, 2);
      dot4(acc, z1, wr, 28, HST, 3);
    }

    // ---- red16 + act + gat ----
    if (isL0 ? (p < NT) : (p >= 2)) {
      float sg[4];
      const int kb = ks & 3;
#pragma unroll
      for (int gt = 0; gt < 4; ++gt) {
        const float r0 = red16(acc[gt][0]);
        const float r1 = red16(acc[gt][1]);
        const float r2 = red16(acc[gt][2]);
        const float r3 = red16(acc[gt][3]);
        sg[gt] = (kb == 0 ? r0 : kb == 1 ? r1 : kb == 2 ? r2 : r3) + bs[gt];
      }
      const float h = lstm_act(sg[0], sg[1], sg[2], sg[3], cell);
      if (ks < 4)
        gat[par * 128 + (isL0 ? 0 : 64) + (bq * 4 + ks) * 8 + u] = h;
    }
    bar_lgkm();  // B3 (gat visible; x prefetch still in flight)

    // ---- publisher tail (wave7): coalesced publish, drain+flag off-path ----
    if (wave == 7) {
      const int L = lane >> 5, idx = lane & 31;
      const bool ok = L ? (p >= 2) : (p < NT);
      if (ok) {
        const u64 v = *reinterpret_cast<const u64*>(
            &gat[par * 128 + L * 64 + idx * 2]);
        float* hb = L ? h1buf : h0buf;
        st_h64(reinterpret_cast<u64*>(hb + par * 16384 + g * 2048 + j * 64 +
                                      idx * 2),
               v);
      }
      asm volatile("s_waitcnt vmcnt(0)" ::: "memory");
      if (lane == 0) st_flag(&fl[j], p + 1);
    }
  }

  // ---- epilogue: FC over relu(h1[NT-1]) by WG j==0 of each group ----
  if (j == 0) {
    if (tid < 32) {
      int guard = 0;
      while (ld_flag(&fl[tid]) < NT + 2) {
        __builtin_amdgcn_s_sleep(1);
        if (++guard > 50000000) break;
      }
    }
    __syncthreads();
    const int bbb = tid >> 6, ln = tid & 63;  // 8 waves = 8 batches
    // h1(NT-1) at parity (NT-1)&1 = 1; cols ln*4..ln*4+3
    const float* src = h1buf + 16384 + g * 2048 + (ln >> 1) * 64 + bbb * 8 +
                       (ln & 1) * 4;
    const u64 u0 = ld_h64(reinterpret_cast<const u64*>(src));
    const u64 u1 = ld_h64(reinterpret_cast<const u64*>(src + 2));
    const float ha = __uint_as_float((unsigned)u0);
    const float hb = __uint_as_float((unsigned)(u0 >> 32));
    const float hc = __uint_as_float((unsigned)u1);
    const float hd = __uint_as_float((unsigned)(u1 >> 32));
    const float4 w4 = *reinterpret_cast<const float4*>(fcw + ln * 4);
    float pr = fmaxf(ha, 0.f) * w4.x + fmaxf(hb, 0.f) * w4.y +
               fmaxf(hc, 0.f) * w4.z + fmaxf(hd, 0.f) * w4.w;
#pragma unroll
    for (int off = 32; off >= 1; off >>= 1) pr += __shfl_down(pr, off, 64);
    if (ln == 0) out[b0 + bbb] = pr + fcb[0];
  }
}

extern "C" void kernel_launch(void* const* d_in, const int* in_sizes, int n_in,
                              void* d_out, int out_size, void* d_ws, size_t ws_size,
                              hipStream_t stream) {
  (void)in_sizes; (void)n_in; (void)out_size; (void)ws_size;
  const float* x    = (const float*)d_in[0];
  const float* wih0 = (const float*)d_in[1];
  const float* whh0 = (const float*)d_in[2];
  const float* bih0 = (const float*)d_in[3];
  const float* bhh0 = (const float*)d_in[4];
  const float* wih1 = (const float*)d_in[5];
  const float* whh1 = (const float*)d_in[6];
  const float* bih1 = (const float*)d_in[7];
  const float* bhh1 = (const float*)d_in[8];
  const float* fcw  = (const float*)d_in[9];
  const float* fcb  = (const float*)d_in[10];
  float* out = (float*)d_out;

  float* ws = (float*)d_ws;
  float* h0buf = ws;                     // [2][8 g][32 j][8 b][8 u]
  float* h1buf = ws + 32768;             // [2][8][32][8][8]
  int* flags = (int*)(ws + 65536);       // [8][32]

  const size_t zbytes = (size_t)65536 * sizeof(float) + 256 * sizeof(int);
  hipMemsetAsync(d_ws, 0, zbytes, stream);

  size_t shmem = 96 * 1024;  // force 1 WG/CU (co-residency, CU exclusivity)
  if (hipFuncSetAttribute(reinterpret_cast<const void*>(lstm_persistent),
                          hipFuncAttributeMaxDynamicSharedMemorySize,
                          (int)shmem) != hipSuccess) {
    shmem = (2 * 8 * XST + 2 * 8 * HST + 8 * HST + 256 + 16) * sizeof(float);
  }

  hipLaunchKernelGGL(lstm_persistent, dim3(256), dim3(512), shmem, stream,
                     x, wih0, whh0, bih0, bhh0, wih1, whh1, bih1, bhh1,
                     fcw, fcb, out, h0buf, h1buf, flags);
}